// Round 1
// baseline (104.550 us; speedup 1.0000x reference)
//
#include <hip/hip_runtime.h>
#include <math.h>

// NodeGate: out[b,n,f] = U[b,n,f] * sigmoid( sum_d silu(mean_f(U[b,n,:])*W1[d]+b1[d]) * W2[d] + b2 )
// B=32, N=4096, F=512, D=64. Pure streaming op; one wave per (b,n) row.

#define FDIM 512
#define DDIM 64

__global__ __launch_bounds__(256) void nodegate_kernel(
    const float* __restrict__ U,
    const float* __restrict__ W1,   // [D,1] flat = [D]
    const float* __restrict__ b1,   // [D]
    const float* __restrict__ W2,   // [1,D] flat = [D]
    const float* __restrict__ b2,   // [1]
    float* __restrict__ out,
    int nrows)
{
    const int lane = threadIdx.x & 63;
    const int wave = threadIdx.x >> 6;
    const int wavesPerBlock = blockDim.x >> 6;
    const int waveId = blockIdx.x * wavesPerBlock + wave;
    const int nWaves = gridDim.x * wavesPerBlock;

    // Tiny gate params: lane d owns element d (D == wave size == 64).
    const float w1  = W1[lane];
    const float bb1 = b1[lane];
    const float w2  = W2[lane];
    const float bb2 = b2[0];

    const float4* __restrict__ src4 = reinterpret_cast<const float4*>(U);
    float4* __restrict__ dst4 = reinterpret_cast<float4*>(out);

    for (int row = waveId; row < nrows; row += nWaves) {
        const size_t base = (size_t)row * (FDIM / 4);
        // Lane-contiguous loads: instr 0 covers floats [0,256), instr 1 covers [256,512).
        float4 v0 = src4[base + lane];
        float4 v1 = src4[base + lane + 64];

        float sum = (v0.x + v0.y) + (v0.z + v0.w)
                  + (v1.x + v1.y) + (v1.z + v1.w);
        // Wave-64 butterfly reduce: all lanes end with the full sum.
        #pragma unroll
        for (int off = 32; off > 0; off >>= 1)
            sum += __shfl_xor(sum, off, 64);

        const float s = sum * (1.0f / (float)FDIM);

        // Excite MLP: lane d computes its hidden unit's contribution.
        const float pre = fmaf(s, w1, bb1);
        const float h = pre / (1.0f + __expf(-pre));   // SiLU
        float c = h * w2;
        #pragma unroll
        for (int off = 32; off > 0; off >>= 1)
            c += __shfl_xor(c, off, 64);

        const float g = 1.0f / (1.0f + __expf(-(c + bb2)));

        v0.x *= g; v0.y *= g; v0.z *= g; v0.w *= g;
        v1.x *= g; v1.y *= g; v1.z *= g; v1.w *= g;
        dst4[base + lane]      = v0;
        dst4[base + lane + 64] = v1;
    }
}

extern "C" void kernel_launch(void* const* d_in, const int* in_sizes, int n_in,
                              void* d_out, int out_size, void* d_ws, size_t ws_size,
                              hipStream_t stream)
{
    const float* U  = (const float*)d_in[0];
    const float* W1 = (const float*)d_in[1];
    const float* b1 = (const float*)d_in[2];
    const float* W2 = (const float*)d_in[3];
    const float* b2 = (const float*)d_in[4];
    float* out = (float*)d_out;

    const int nrows = in_sizes[0] / FDIM;       // B*N = 131072
    const int threads = 256;                    // 4 waves/block
    const int wavesPerBlock = threads / 64;
    int blocks = (nrows + wavesPerBlock - 1) / wavesPerBlock;
    if (blocks > 2048) blocks = 2048;           // grid-stride the rest

    hipLaunchKernelGGL(nodegate_kernel, dim3(blocks), dim3(threads), 0, stream,
                       U, W1, b1, W2, b2, out, nrows);
}

// Round 2
// 92.682 us; speedup vs baseline: 1.1281x; 1.1281x over previous
//
#include <hip/hip_runtime.h>
#include <math.h>

// NodeGate: out[b,n,f] = U[b,n,f] * sigmoid( sum_d silu(mean_f(U[b,n,:])*W1[d]+b1[d]) * W2[d] + b2 )
// B=32, N=4096, F=512, D=64. Pure streaming; one wave handles 2 rows/iter
// (independent reduce chains for ILP), nontemporal loads/stores.

#define FDIM 512

typedef float v4f __attribute__((ext_vector_type(4)));

__global__ __launch_bounds__(256) void nodegate_kernel(
    const float* __restrict__ U,
    const float* __restrict__ W1,   // [D]
    const float* __restrict__ b1,   // [D]
    const float* __restrict__ W2,   // [D]
    const float* __restrict__ b2,   // [1]
    float* __restrict__ out,
    int npairs)                      // nrows / 2
{
    const int lane = threadIdx.x & 63;
    const int wave = threadIdx.x >> 6;
    const int wavesPerBlock = blockDim.x >> 6;
    const int waveId = blockIdx.x * wavesPerBlock + wave;
    const int nWaves = gridDim.x * wavesPerBlock;

    // Gate params: lane d owns hidden unit d (D == 64 == wave size).
    const float w1  = W1[lane];
    const float bb1 = b1[lane];
    const float w2  = W2[lane];
    const float bb2 = b2[0];

    const v4f* __restrict__ src4 = reinterpret_cast<const v4f*>(U);
    v4f* __restrict__ dst4 = reinterpret_cast<v4f*>(out);

    for (int p = waveId; p < npairs; p += nWaves) {
        const size_t base = (size_t)p * 2 * (FDIM / 4);
        // Row A = 2p, Row B = 2p+1. 4 KB contiguous per wave per iteration.
        v4f a0 = __builtin_nontemporal_load(&src4[base + lane]);
        v4f a1 = __builtin_nontemporal_load(&src4[base + lane + 64]);
        v4f c0 = __builtin_nontemporal_load(&src4[base + lane + 128]);
        v4f c1 = __builtin_nontemporal_load(&src4[base + lane + 192]);

        float sa = (a0.x + a0.y) + (a0.z + a0.w) + (a1.x + a1.y) + (a1.z + a1.w);
        float sb = (c0.x + c0.y) + (c0.z + c0.w) + (c1.x + c1.y) + (c1.z + c1.w);

        // Two independent wave-64 butterflies, interleaved by the compiler.
        #pragma unroll
        for (int off = 32; off > 0; off >>= 1) {
            sa += __shfl_xor(sa, off, 64);
            sb += __shfl_xor(sb, off, 64);
        }

        const float ma = sa * (1.0f / (float)FDIM);
        const float mb = sb * (1.0f / (float)FDIM);

        // Excite MLP, lane d computes hidden unit d's contribution.
        const float pa = fmaf(ma, w1, bb1);
        const float pb = fmaf(mb, w1, bb1);
        const float ha = pa / (1.0f + __expf(-pa));     // SiLU
        const float hb = pb / (1.0f + __expf(-pb));
        float da = ha * w2;
        float db = hb * w2;
        #pragma unroll
        for (int off = 32; off > 0; off >>= 1) {
            da += __shfl_xor(da, off, 64);
            db += __shfl_xor(db, off, 64);
        }

        const float ga = 1.0f / (1.0f + __expf(-(da + bb2)));
        const float gb = 1.0f / (1.0f + __expf(-(db + bb2)));

        a0 *= ga; a1 *= ga; c0 *= gb; c1 *= gb;
        __builtin_nontemporal_store(a0, &dst4[base + lane]);
        __builtin_nontemporal_store(a1, &dst4[base + lane + 64]);
        __builtin_nontemporal_store(c0, &dst4[base + lane + 128]);
        __builtin_nontemporal_store(c1, &dst4[base + lane + 192]);
    }
}

extern "C" void kernel_launch(void* const* d_in, const int* in_sizes, int n_in,
                              void* d_out, int out_size, void* d_ws, size_t ws_size,
                              hipStream_t stream)
{
    const float* U  = (const float*)d_in[0];
    const float* W1 = (const float*)d_in[1];
    const float* b1 = (const float*)d_in[2];
    const float* W2 = (const float*)d_in[3];
    const float* b2 = (const float*)d_in[4];
    float* out = (float*)d_out;

    const int nrows = in_sizes[0] / FDIM;       // B*N = 131072
    const int npairs = nrows / 2;               // 65536 (even by construction)
    const int threads = 256;                    // 4 waves/block
    const int wavesPerBlock = threads / 64;
    int blocks = (npairs + wavesPerBlock - 1) / wavesPerBlock;
    if (blocks > 2048) blocks = 2048;           // grid-stride the rest

    hipLaunchKernelGGL(nodegate_kernel, dim3(blocks), dim3(threads), 0, stream,
                       U, W1, b1, W2, b2, out, npairs);
}